// Round 6
// baseline (332.704 us; speedup 1.0000x reference)
//
#include <hip/hip_runtime.h>
#include <math.h>

// Problem constants (fixed by the reference).
#define NUM_K   512        // codebook entries
#define DIM     64         // embedding dim (== C)
#define NROWS   131072     // 32*64*64 flattened (b,h,w) rows
#define NELEM   8388608    // NROWS*DIM
// d_out layout (float32, concatenated in return order):
// [0] loss ; [1..1+NELEM) quantized NCHW ; [1+NELEM] perplexity ;
// [2+NELEM..) codebook_indices (as float)
#define Q_OFF    1
#define PERP_OFF 8388609
#define IDX_OFF  8388610

// Flag threshold: ref rounding noise ~2*ulp(64)=1.5e-5, our mfma-split dot
// error <~1e-5 worst case -> 1.25e-4 gives ~3x safety margin. Rows with
// approx gap >= THRESH provably share the reference argmin; others re-done
// exactly (frozen bitwise path) in vq_exact.
#define THRESH  1.25e-4f

typedef short  bf16x8 __attribute__((ext_vector_type(8)));
typedef float  f32x4  __attribute__((ext_vector_type(4)));

// ws layout:
//   [0,4)        float loss_sum
//   [4,8)        uint  nflag
//   [16,2064)    uint  counts[512]
//   [4096,6144)  float swsq_g[512]          (frozen bitwise ||w_k||^2)
//   [8192,139264)  ushort wpack[65536]      (B-fragment-packed hi/lo codebook)
//   [139264,663552) uint flaglist[131072]
// total ~664 KB.

__device__ __forceinline__ unsigned short f2bf(float f) {  // RNE f32->bf16
    unsigned u = __float_as_uint(f);
    return (unsigned short)((u + 0x7FFFu + ((u >> 16) & 1u)) >> 16);
}
__device__ __forceinline__ float bf2f(unsigned short h) {
    return __uint_as_float(((unsigned)h) << 16);
}

// Prep: frozen wsq (bitwise numpy pairwise leaf, verified round 2) + pack the
// codebook as bf16 hi/lo in exact B-fragment order for mfma_f32_16x16x32_bf16:
// B[k = (lane>>4)*8 + j][n = lane&15], frag index f = step*2 + pass.
__global__ __launch_bounds__(256) void vq_prep(const float* __restrict__ w,
                                               float* __restrict__ swsq_g,
                                               unsigned short* __restrict__ wpack) {
    const int id = blockIdx.x * 256 + threadIdx.x;   // 0..8191
    if (id < NUM_K) {
        const float* wk = w + id * DIM;
        float r[8];
#pragma unroll
        for (int j = 0; j < 8; ++j) r[j] = __fmul_rn(wk[j], wk[j]);
#pragma unroll
        for (int t = 1; t < 8; ++t)
#pragma unroll
            for (int j = 0; j < 8; ++j)
                r[j] = __fadd_rn(r[j], __fmul_rn(wk[8 * t + j], wk[8 * t + j]));
        swsq_g[id] = __fadd_rn(
            __fadd_rn(__fadd_rn(r[0], r[1]), __fadd_rn(r[2], r[3])),
            __fadd_rn(__fadd_rn(r[4], r[5]), __fadd_rn(r[6], r[7])));
    }
    // wpack element: id = ((kt*4 + f)*64 + lane)
    const int kt = id >> 8, f = (id >> 6) & 3, l = id & 63;
    const int step = f >> 1, pass = f & 1;
    const int coln = kt * 16 + (l & 15), quad = l >> 4;
    const float* src = w + (size_t)coln * DIM + step * 32 + quad * 8;
    unsigned short tmp[8];
#pragma unroll
    for (int j = 0; j < 8; ++j) {
        float v = src[j];
        unsigned short hi = f2bf(v);
        tmp[j] = pass ? f2bf(v - bf2f(hi)) : hi;
    }
    *(uint4*)(wpack + (size_t)id * 8) = *(uint4*)tmp;
}

// Phase 1: MFMA filter. Block = 256 thr (4 waves) = 64 rows; wave = 16-row
// tile; k-loop over 32 col-tiles of 16 codes. acc = x_hi*w_hi + x_hi*w_lo +
// x_lo*w_hi (fp32 MFMA accumulate). Layouts (verified, guide §3):
//   A[m=lane&15][k=(lane>>4)*8+j] ; C/D: col=lane&15, row=(lane>>4)*4+reg.
__global__ __launch_bounds__(256, 4) void vq_phase1(
        const float* __restrict__ x,
        const float* __restrict__ w,
        const float* __restrict__ swsq_g,
        const uint4* __restrict__ wpack,
        float* __restrict__ out_q,
        float* __restrict__ out_idx,
        float* __restrict__ loss_sum,
        unsigned* __restrict__ counts,
        unsigned* __restrict__ nflag,
        unsigned* __restrict__ flaglist) {
    __shared__ float xs[DIM * 64];                     // xs[c][row] fp32 16 KB
    __shared__ __align__(16) unsigned short af[8192];  // A frags 16 KB; reused as B-tile buf
    __shared__ float xsqp[4 * 64];
    __shared__ float sxsq[64];
    __shared__ float swsq[NUM_K];
    __shared__ unsigned hcnt[NUM_K];
    __shared__ int sidx[64];
    __shared__ float wred[4];

    const int tid  = threadIdx.x;
    const int lane = tid & 63;
    const int wvid = tid >> 6;            // wave id = row tile (16 rows)
    const int n0   = blockIdx.x * 64;
    const int b    = n0 >> 12;
    const int hw0  = n0 & 4095;
    const float* xbase = x + (size_t)b * 262144 + hw0;

    for (int i = tid; i < NUM_K; i += 256) { swsq[i] = swsq_g[i]; hcnt[i] = 0; }

    // Stage x: thread (row=tid&63, cg=tid>>6) loads 16 channels (coalesced),
    // writes fp32 to xs and bf16 hi/lo into A-fragment layout.
    {
        const int row = tid & 63, cg = tid >> 6;
        const int tile = row >> 4, m = row & 15;
        float p = 0.f;
#pragma unroll
        for (int j = 0; j < 16; ++j) {
            const int c = cg * 16 + j;
            float v = xbase[(size_t)c * 4096 + row];
            xs[c * 64 + row] = v;
            p = fmaf(v, v, p);
            unsigned short hi = f2bf(v);
            unsigned short lo = f2bf(v - bf2f(hi));
            const int step = c >> 5, kk = c & 31, quad = kk >> 3, jj = kk & 7;
            const int lf = quad * 16 + m;
            const int q0 = ((tile * 2 + step) * 2) * 512;   // pass0 frag base
            af[q0 + lf * 8 + jj] = hi;
            af[q0 + 512 + lf * 8 + jj] = lo;                // pass1 frag
        }
        xsqp[cg * 64 + row] = p;
    }
    __syncthreads();   // B1: staging complete

    if (tid < 64)
        sxsq[tid] = (xsqp[tid] + xsqp[64 + tid]) + (xsqp[128 + tid] + xsqp[192 + tid]);

    // A fragments -> registers (reused across all 32 k-tiles).
    bf16x8 afr[2][2];
#pragma unroll
    for (int s = 0; s < 2; ++s)
#pragma unroll
        for (int pp = 0; pp < 2; ++pp)
            afr[s][pp] = *(const bf16x8*)&af[(((wvid * 2 + s) * 2 + pp) * 64 + lane) * 8];
    __syncthreads();   // B2: sxsq ready, af region free for B tiles

    float xsq4[4];
#pragma unroll
    for (int r = 0; r < 4; ++r)
        xsq4[r] = sxsq[wvid * 16 + (lane >> 4) * 4 + r];

    float min1[4], min2[4]; int idx[4];
#pragma unroll
    for (int r = 0; r < 4; ++r) { min1[r] = 3.4e38f; min2[r] = 3.4e38f; idx[r] = 0; }

    for (int kt = 0; kt < 32; ++kt) {
        // Stage this col-tile's B fragments (4 KB) into the af buffer.
        uint4 t16 = wpack[(size_t)kt * 256 + tid];
        *(uint4*)&af[tid * 8] = t16;
        __syncthreads();
        bf16x8 bfr[2][2];
#pragma unroll
        for (int s = 0; s < 2; ++s)
#pragma unroll
            for (int pp = 0; pp < 2; ++pp)
                bfr[s][pp] = *(const bf16x8*)&af[((s * 2 + pp) * 64 + lane) * 8];

        f32x4 acc = {0.f, 0.f, 0.f, 0.f};
        acc = __builtin_amdgcn_mfma_f32_16x16x32_bf16(afr[0][0], bfr[0][0], acc, 0, 0, 0);
        acc = __builtin_amdgcn_mfma_f32_16x16x32_bf16(afr[0][0], bfr[0][1], acc, 0, 0, 0);
        acc = __builtin_amdgcn_mfma_f32_16x16x32_bf16(afr[0][1], bfr[0][0], acc, 0, 0, 0);
        acc = __builtin_amdgcn_mfma_f32_16x16x32_bf16(afr[1][0], bfr[1][0], acc, 0, 0, 0);
        acc = __builtin_amdgcn_mfma_f32_16x16x32_bf16(afr[1][0], bfr[1][1], acc, 0, 0, 0);
        acc = __builtin_amdgcn_mfma_f32_16x16x32_bf16(afr[1][1], bfr[1][0], acc, 0, 0, 0);

        const int kg = kt * 16 + (lane & 15);
        const float wsqv = swsq[kg];
#pragma unroll
        for (int r = 0; r < 4; ++r) {
            float s = fmaf(-2.f, acc[r], xsq4[r] + wsqv);
            bool lt = s < min1[r];
            min2[r] = fminf(min2[r], lt ? min1[r] : s);
            idx[r]  = lt ? kg : idx[r];
            min1[r] = fminf(min1[r], s);
        }
        __syncthreads();   // before next tile overwrites the B buffer
    }

    // Reduce (min1,min2,idx) across the 16 col-classes (lanes sharing lane>>4).
#pragma unroll
    for (int d = 1; d < 16; d <<= 1) {
#pragma unroll
        for (int r = 0; r < 4; ++r) {
            float o1 = __shfl_xor(min1[r], d);
            float o2 = __shfl_xor(min2[r], d);
            int   oi = __shfl_xor(idx[r], d);
            if (o1 < min1[r]) { min2[r] = fminf(min1[r], o2); min1[r] = o1; idx[r] = oi; }
            else              { min2[r] = fminf(min2[r], o1); }
        }
    }
    if ((lane & 15) == 0) {
#pragma unroll
        for (int r = 0; r < 4; ++r) {
            const int rowg = wvid * 16 + (lane >> 4) * 4 + r;
            const bool fl = (min2[r] - min1[r]) < THRESH;
            sidx[rowg] = fl ? -1 : idx[r];
            if (fl) {
                unsigned gi = atomicAdd(nflag, 1u);
                flaglist[gi] = (unsigned)(n0 + rowg);
            }
        }
    }
    __syncthreads();   // B4: sidx ready

    // Epilogue for unflagged rows (flagged handled by vq_exact/vq_flagfix).
    {
        const int row = tid & 63, cg = tid >> 6;
        const int bk = sidx[row];
        float dsum = 0.f;
        if (bk >= 0) {
            const float4* wb = (const float4*)(w + (size_t)bk * DIM + cg * 16);
            float* oq = out_q + (size_t)b * 262144 + hw0 + row;
#pragma unroll
            for (int j4 = 0; j4 < 4; ++j4) {
                float4 v = wb[j4];
                const int c = cg * 16 + j4 * 4;
                float e0 = v.x - xs[(c + 0) * 64 + row];
                float e1 = v.y - xs[(c + 1) * 64 + row];
                float e2 = v.z - xs[(c + 2) * 64 + row];
                float e3 = v.w - xs[(c + 3) * 64 + row];
                dsum = fmaf(e0, e0, dsum);
                dsum = fmaf(e1, e1, dsum);
                dsum = fmaf(e2, e2, dsum);
                dsum = fmaf(e3, e3, dsum);
                oq[(size_t)(c + 0) * 4096] = v.x;
                oq[(size_t)(c + 1) * 4096] = v.y;
                oq[(size_t)(c + 2) * 4096] = v.z;
                oq[(size_t)(c + 3) * 4096] = v.w;
            }
            if (cg == 0) {
                out_idx[n0 + row] = (float)bk;
                atomicAdd(&hcnt[bk], 1u);
            }
        }
#pragma unroll
        for (int off = 32; off > 0; off >>= 1) dsum += __shfl_down(dsum, off);
        if (lane == 0) wred[wvid] = dsum;
    }
    __syncthreads();
    if (tid == 0)
        atomicAdd(loss_sum, (wred[0] + wred[1]) + (wred[2] + wred[3]));
    for (int i = tid; i < NUM_K; i += 256) {
        unsigned cc = hcnt[i];
        if (cc) atomicAdd(&counts[i], cc);
    }
}

// Phase 2: exact frozen (round-2 bitwise-verified) rescan of flagged rows.
// One wave per row, grid-stride. Tie rule: lexicographic (s,k) = np.argmin.
__global__ __launch_bounds__(64) void vq_exact(
        const float* __restrict__ x, const float* __restrict__ w,
        const unsigned* __restrict__ nflag, const unsigned* __restrict__ flaglist,
        float* __restrict__ out_idx) {
    __shared__ float xrow[DIM];
    const int lane = threadIdx.x;
    const unsigned nf = *nflag;
    for (unsigned fi = blockIdx.x; fi < nf; fi += gridDim.x) {
        const int n = (int)flaglist[fi];
        const int b = n >> 12, hw = n & 4095;
        xrow[lane] = x[(size_t)b * 262144 + (size_t)lane * 4096 + hw];
        __syncthreads();
        // frozen xsq (p_i over c===i mod 4, ascending; fixed combine)
        float p0 = 0.f, p1 = 0.f, p2 = 0.f, p3 = 0.f;
#pragma unroll
        for (int c = 0; c < DIM; c += 4) {
            p0 = fmaf(xrow[c + 0], xrow[c + 0], p0);
            p1 = fmaf(xrow[c + 1], xrow[c + 1], p1);
            p2 = fmaf(xrow[c + 2], xrow[c + 2], p2);
            p3 = fmaf(xrow[c + 3], xrow[c + 3], p3);
        }
        const float xsq = __fadd_rn(__fadd_rn(p0, p1), __fadd_rn(p2, p3));
        float best = 3.4e38f; int bk = 1 << 30;
        for (int t = 0; t < 8; ++t) {
            const int k = lane + 64 * t;
            const float* wk = w + (size_t)k * DIM;
            float r[8];
#pragma unroll
            for (int j = 0; j < 8; ++j) r[j] = __fmul_rn(wk[j], wk[j]);
#pragma unroll
            for (int tt = 1; tt < 8; ++tt)
#pragma unroll
                for (int j = 0; j < 8; ++j)
                    r[j] = __fadd_rn(r[j], __fmul_rn(wk[8 * tt + j], wk[8 * tt + j]));
            const float wsq = __fadd_rn(
                __fadd_rn(__fadd_rn(r[0], r[1]), __fadd_rn(r[2], r[3])),
                __fadd_rn(__fadd_rn(r[4], r[5]), __fadd_rn(r[6], r[7])));
            float d = 0.f;
#pragma unroll
            for (int c = 0; c < DIM; ++c) d = fmaf(xrow[c], wk[c], d);
            const float s = __fsub_rn(__fadd_rn(xsq, wsq), __fmul_rn(2.f, d));
            if (s < best || (s == best && k < bk)) { best = s; bk = k; }
        }
#pragma unroll
        for (int d = 1; d < 64; d <<= 1) {
            float ob = __shfl_xor(best, d);
            int   oi = __shfl_xor(bk, d);
            if (ob < best || (ob == best && oi < bk)) { best = ob; bk = oi; }
        }
        if (lane == 0) out_idx[n] = (float)bk;
        __syncthreads();
    }
}

// Phase 3: epilogue for flagged rows (quantized write, loss, histogram).
__global__ __launch_bounds__(64) void vq_flagfix(
        const float* __restrict__ x, const float* __restrict__ w,
        const unsigned* __restrict__ nflag, const unsigned* __restrict__ flaglist,
        const float* __restrict__ out_idx, float* __restrict__ out_q,
        float* __restrict__ loss_sum, unsigned* __restrict__ counts) {
    const int lane = threadIdx.x;
    const unsigned nf = *nflag;
    for (unsigned fi = blockIdx.x; fi < nf; fi += gridDim.x) {
        const int n = (int)flaglist[fi];
        const int b = n >> 12, hw = n & 4095;
        const int bk = (int)out_idx[n];
        const size_t off = (size_t)b * 262144 + (size_t)lane * 4096 + hw;
        const float wv = w[(size_t)bk * DIM + lane];
        const float xv = x[off];
        out_q[off] = wv;
        float e = wv - xv;
        float e2 = e * e;
#pragma unroll
        for (int d = 32; d > 0; d >>= 1) e2 += __shfl_down(e2, d);
        if (lane == 0) { atomicAdd(loss_sum, e2); atomicAdd(&counts[bk], 1u); }
    }
}

__global__ __launch_bounds__(512) void vq_final(
        const unsigned* __restrict__ counts,
        const float* __restrict__ loss_sum,
        float* __restrict__ out) {
    __shared__ float red[8];
    const int tid = threadIdx.x;
    float p = (float)counts[tid] * (1.f / (float)NROWS);  // /131072 exact
    float t = p * logf(p + 1e-10f);
#pragma unroll
    for (int off = 32; off > 0; off >>= 1) t += __shfl_down(t, off);
    if ((tid & 63) == 0) red[tid >> 6] = t;
    __syncthreads();
    if (tid == 0) {
        float s = 0.f;
#pragma unroll
        for (int i = 0; i < 8; ++i) s += red[i];
        out[PERP_OFF] = expf(-s);
        // loss = q_latent + 0.25*e_latent = 1.25 * MSE (forward values equal)
        out[0] = loss_sum[0] * (1.25f / (float)NELEM);
    }
}

extern "C" void kernel_launch(void* const* d_in, const int* in_sizes, int n_in,
                              void* d_out, int out_size, void* d_ws, size_t ws_size,
                              hipStream_t stream) {
    const float* x = (const float*)d_in[0];
    const float* w = (const float*)d_in[1];
    float* out = (float*)d_out;
    char* ws = (char*)d_ws;
    float*    loss_sum = (float*)ws;
    unsigned* nflag    = (unsigned*)(ws + 4);
    unsigned* counts   = (unsigned*)(ws + 16);
    float*    swsq_g   = (float*)(ws + 4096);
    unsigned short* wpack = (unsigned short*)(ws + 8192);
    unsigned* flaglist = (unsigned*)(ws + 139264);

    // ws re-poisoned to 0xAA each launch: zero loss/nflag/counts.
    hipMemsetAsync(d_ws, 0, 2064, stream);

    vq_prep<<<32, 256, 0, stream>>>(w, swsq_g, wpack);
    vq_phase1<<<NROWS / 64, 256, 0, stream>>>(x, w, swsq_g, (const uint4*)wpack,
                                              out + Q_OFF, out + IDX_OFF,
                                              loss_sum, counts, nflag, flaglist);
    vq_exact<<<1024, 64, 0, stream>>>(x, w, nflag, flaglist, out + IDX_OFF);
    vq_flagfix<<<1024, 64, 0, stream>>>(x, w, nflag, flaglist, out + IDX_OFF,
                                        out + Q_OFF, loss_sum, counts);
    vq_final<<<1, 512, 0, stream>>>(counts, loss_sum, out);
}

// Round 7
// 254.139 us; speedup vs baseline: 1.3091x; 1.3091x over previous
//
#include <hip/hip_runtime.h>
#include <math.h>

// Problem constants (fixed by the reference).
#define NUM_K   512        // codebook entries
#define DIM     64         // embedding dim (== C)
#define NROWS   131072     // 32*64*64 flattened (b,h,w) rows
#define NELEM   8388608    // NROWS*DIM
// d_out layout (float32, concatenated in return order):
// [0] loss ; [1..1+NELEM) quantized NCHW ; [1+NELEM] perplexity ;
// [2+NELEM..) codebook_indices (as float)
#define Q_OFF    1
#define PERP_OFF 8388609
#define IDX_OFF  8388610

// Flag threshold (validated round 6): rows with approx gap >= THRESH provably
// share the reference argmin; others re-done bitwise-exactly in vq_exact.
#define THRESH  1.25e-4f

typedef short  bf16x8 __attribute__((ext_vector_type(8)));
typedef float  f32x4  __attribute__((ext_vector_type(4)));

// ws layout:
//   [0,4)        float loss_sum
//   [4,8)        uint  nflag
//   [16,2064)    uint  counts[512]
//   [4096,6144)  float swsq_g[512]          (frozen bitwise ||w_k||^2)
//   [8192,139264)  ushort wpack[65536]      (B-fragment-packed hi/lo codebook)
//   [139264,663552) uint flaglist[131072]

__device__ __forceinline__ unsigned short f2bf(float f) {  // RNE f32->bf16
    unsigned u = __float_as_uint(f);
    return (unsigned short)((u + 0x7FFFu + ((u >> 16) & 1u)) >> 16);
}
__device__ __forceinline__ float bf2f(unsigned short h) {
    return __uint_as_float(((unsigned)h) << 16);
}

// Prep (UNCHANGED from round 6 — validated): frozen wsq + B-fragment packing
// for mfma_f32_16x16x32_bf16: B[k=(lane>>4)*8+j][n=lane&15], f = step*2+pass.
__global__ __launch_bounds__(256) void vq_prep(const float* __restrict__ w,
                                               float* __restrict__ swsq_g,
                                               unsigned short* __restrict__ wpack) {
    const int id = blockIdx.x * 256 + threadIdx.x;   // 0..8191
    if (id < NUM_K) {
        const float* wk = w + id * DIM;
        float r[8];
#pragma unroll
        for (int j = 0; j < 8; ++j) r[j] = __fmul_rn(wk[j], wk[j]);
#pragma unroll
        for (int t = 1; t < 8; ++t)
#pragma unroll
            for (int j = 0; j < 8; ++j)
                r[j] = __fadd_rn(r[j], __fmul_rn(wk[8 * t + j], wk[8 * t + j]));
        swsq_g[id] = __fadd_rn(
            __fadd_rn(__fadd_rn(r[0], r[1]), __fadd_rn(r[2], r[3])),
            __fadd_rn(__fadd_rn(r[4], r[5]), __fadd_rn(r[6], r[7])));
    }
    const int kt = id >> 8, f = (id >> 6) & 3, l = id & 63;
    const int step = f >> 1, pass = f & 1;
    const int coln = kt * 16 + (l & 15), quad = l >> 4;
    const float* src = w + (size_t)coln * DIM + step * 32 + quad * 8;
    unsigned short tmp[8];
#pragma unroll
    for (int j = 0; j < 8; ++j) {
        float v = src[j];
        unsigned short hi = f2bf(v);
        tmp[j] = pass ? f2bf(v - bf2f(hi)) : hi;
    }
    *(uint4*)(wpack + (size_t)id * 8) = *(uint4*)tmp;
}

// Phase 1: MFMA filter, barrier-free k-loop.
// Block = 256 thr (4 waves); wave owns 32 rows (2 row-tiles of 16); block =
// 128 rows; grid = 1024. A fragments built in registers from global x.
// B fragments read directly from wpack (already fragment-ordered, coalesced,
// L2-hot), prefetched one tile ahead. Score s' = wsq[k] - 2*dot (xsq dropped:
// argmin & gap invariant). acc = xh*wh + xh*wl + xl*wh in fp32 MFMA.
__global__ __launch_bounds__(256, 3) void vq_phase1(
        const float* __restrict__ x,
        const float* __restrict__ w,
        const float* __restrict__ swsq_g,
        const uint4* __restrict__ wpack,
        float* __restrict__ out_q,
        float* __restrict__ out_idx,
        float* __restrict__ loss_sum,
        unsigned* __restrict__ counts,
        unsigned* __restrict__ nflag,
        unsigned* __restrict__ flaglist) {
    __shared__ float swsq[NUM_K];          // 2 KB
    __shared__ unsigned hcnt[NUM_K];       // 2 KB
    __shared__ int sidx[128];
    __shared__ float wred[4];

    const int tid  = threadIdx.x;
    const int lane = tid & 63;
    const int wvid = tid >> 6;
    const int quad = lane >> 4;
    const int m    = lane & 15;
    const int n0   = blockIdx.x * 128;
    const int b    = n0 >> 12;
    const int hw0  = n0 & 4095;
    const float* xbase = x + (size_t)b * 262144 + hw0;

    for (int i = tid; i < NUM_K; i += 256) { swsq[i] = swsq_g[i]; hcnt[i] = 0; }

    // Prefetch first B tile (4 frags) while staging A.
    uint4 nb0 = wpack[0 * 64 + lane];
    uint4 nb1 = wpack[1 * 64 + lane];
    uint4 nb2 = wpack[2 * 64 + lane];
    uint4 nb3 = wpack[3 * 64 + lane];

    // A fragments in registers: afr[rt][step][pass], rt=row-tile (16 rows).
    bf16x8 afr[2][2][2];
#pragma unroll
    for (int rt = 0; rt < 2; ++rt) {
        const int row = wvid * 32 + rt * 16 + m;
        const float* xp = xbase + row;
#pragma unroll
        for (int s = 0; s < 2; ++s) {
            union { bf16x8 v; unsigned short u[8]; } hi, lo;
#pragma unroll
            for (int j = 0; j < 8; ++j) {
                float v = xp[(size_t)(s * 32 + quad * 8 + j) * 4096];
                unsigned short h = f2bf(v);
                hi.u[j] = h;
                lo.u[j] = f2bf(v - bf2f(h));
            }
            afr[rt][s][0] = hi.v;
            afr[rt][s][1] = lo.v;
        }
    }
    __syncthreads();   // swsq/hcnt ready

    float min1[2][4], min2[2][4]; int idx[2][4];
#pragma unroll
    for (int rt = 0; rt < 2; ++rt)
#pragma unroll
        for (int r = 0; r < 4; ++r) {
            min1[rt][r] = 3.4e38f; min2[rt][r] = 3.4e38f; idx[rt][r] = 0;
        }

#pragma unroll 1
    for (int kt = 0; kt < 32; ++kt) {
        uint4 c0 = nb0, c1 = nb1, c2 = nb2, c3 = nb3;
        if (kt < 31) {
            const uint4* np = wpack + (size_t)(kt + 1) * 256;
            nb0 = np[0 * 64 + lane];
            nb1 = np[1 * 64 + lane];
            nb2 = np[2 * 64 + lane];
            nb3 = np[3 * 64 + lane];
        }
        bf16x8 bh0 = __builtin_bit_cast(bf16x8, c0);   // step0 hi
        bf16x8 bl0 = __builtin_bit_cast(bf16x8, c1);   // step0 lo
        bf16x8 bh1 = __builtin_bit_cast(bf16x8, c2);   // step1 hi
        bf16x8 bl1 = __builtin_bit_cast(bf16x8, c3);   // step1 lo

        const int kg = kt * 16 + m;
        const float wsqv = swsq[kg];   // 16 addrs, 4-lane broadcast: no conflict

#pragma unroll
        for (int rt = 0; rt < 2; ++rt) {
            f32x4 acc = {0.f, 0.f, 0.f, 0.f};
            acc = __builtin_amdgcn_mfma_f32_16x16x32_bf16(afr[rt][0][0], bh0, acc, 0, 0, 0);
            acc = __builtin_amdgcn_mfma_f32_16x16x32_bf16(afr[rt][0][0], bl0, acc, 0, 0, 0);
            acc = __builtin_amdgcn_mfma_f32_16x16x32_bf16(afr[rt][0][1], bh0, acc, 0, 0, 0);
            acc = __builtin_amdgcn_mfma_f32_16x16x32_bf16(afr[rt][1][0], bh1, acc, 0, 0, 0);
            acc = __builtin_amdgcn_mfma_f32_16x16x32_bf16(afr[rt][1][0], bl1, acc, 0, 0, 0);
            acc = __builtin_amdgcn_mfma_f32_16x16x32_bf16(afr[rt][1][1], bh1, acc, 0, 0, 0);
#pragma unroll
            for (int r = 0; r < 4; ++r) {
                float s = fmaf(-2.f, acc[r], wsqv);
                bool lt = s < min1[rt][r];
                min2[rt][r] = fminf(min2[rt][r], lt ? min1[rt][r] : s);
                idx[rt][r]  = lt ? kg : idx[rt][r];
                min1[rt][r] = fminf(min1[rt][r], s);
            }
        }
    }

    // Reduce across the 16 k-columns (low 4 lane bits).
#pragma unroll
    for (int d = 1; d < 16; d <<= 1) {
#pragma unroll
        for (int rt = 0; rt < 2; ++rt)
#pragma unroll
            for (int r = 0; r < 4; ++r) {
                float o1 = __shfl_xor(min1[rt][r], d);
                float o2 = __shfl_xor(min2[rt][r], d);
                int   oi = __shfl_xor(idx[rt][r], d);
                if (o1 < min1[rt][r]) {
                    min2[rt][r] = fminf(min1[rt][r], o2);
                    min1[rt][r] = o1; idx[rt][r] = oi;
                } else {
                    min2[rt][r] = fminf(min2[rt][r], o1);
                }
            }
    }
    if (m == 0) {
#pragma unroll
        for (int rt = 0; rt < 2; ++rt)
#pragma unroll
            for (int r = 0; r < 4; ++r) {
                const int rowg = wvid * 32 + rt * 16 + quad * 4 + r;
                const bool fl = (min2[rt][r] - min1[rt][r]) < THRESH;
                sidx[rowg] = fl ? -1 : idx[rt][r];
                if (fl) {
                    unsigned gi = atomicAdd(nflag, 1u);
                    flaglist[gi] = (unsigned)(n0 + rowg);
                } else {
                    atomicAdd(&hcnt[idx[rt][r]], 1u);
                }
            }
    }
    __syncthreads();   // sidx ready

    // Epilogue for unflagged rows: thread (rb=tid&127, cg=tid>>7) writes 32
    // channels of row rb; x re-read from global (L3-hot), coalesced.
    {
        const int rb = tid & 127, cg = tid >> 7;
        const int bk = sidx[rb];
        float dsum = 0.f;
        if (bk >= 0) {
            const float4* wb = (const float4*)(w + (size_t)bk * DIM + cg * 32);
            const float* xq = xbase + rb;
            float* oq = out_q + (size_t)b * 262144 + hw0 + rb;
#pragma unroll
            for (int j4 = 0; j4 < 8; ++j4) {
                float4 v = wb[j4];
                const size_t c = (size_t)(cg * 32 + j4 * 4) * 4096;
                float e0 = v.x - xq[c];
                float e1 = v.y - xq[c + 4096];
                float e2 = v.z - xq[c + 8192];
                float e3 = v.w - xq[c + 12288];
                dsum = fmaf(e0, e0, dsum);
                dsum = fmaf(e1, e1, dsum);
                dsum = fmaf(e2, e2, dsum);
                dsum = fmaf(e3, e3, dsum);
                oq[c] = v.x;
                oq[c + 4096] = v.y;
                oq[c + 8192] = v.z;
                oq[c + 12288] = v.w;
            }
            if (cg == 0) out_idx[n0 + rb] = (float)bk;
        }
#pragma unroll
        for (int off = 32; off > 0; off >>= 1) dsum += __shfl_down(dsum, off);
        if (lane == 0) wred[wvid] = dsum;
    }
    __syncthreads();
    if (tid == 0)
        atomicAdd(loss_sum, (wred[0] + wred[1]) + (wred[2] + wred[3]));
    for (int i = tid; i < NUM_K; i += 256) {
        unsigned cc = hcnt[i];
        if (cc) atomicAdd(&counts[i], cc);
    }
}

// Phase 2: exact frozen rescan of flagged rows (bitwise-verified arithmetic).
// wsq from swsq_g (bitwise-identical prep values). One wave/row, grid-stride.
__global__ __launch_bounds__(64) void vq_exact(
        const float* __restrict__ x, const float* __restrict__ w,
        const float* __restrict__ swsq_g,
        const unsigned* __restrict__ nflag, const unsigned* __restrict__ flaglist,
        float* __restrict__ out_idx) {
    __shared__ float xrow[DIM];
    const int lane = threadIdx.x;
    const unsigned nf = *nflag;
    for (unsigned fi = blockIdx.x; fi < nf; fi += gridDim.x) {
        const int n = (int)flaglist[fi];
        const int b = n >> 12, hw = n & 4095;
        xrow[lane] = x[(size_t)b * 262144 + (size_t)lane * 4096 + hw];
        __syncthreads();
        float p0 = 0.f, p1 = 0.f, p2 = 0.f, p3 = 0.f;
#pragma unroll
        for (int c = 0; c < DIM; c += 4) {
            p0 = fmaf(xrow[c + 0], xrow[c + 0], p0);
            p1 = fmaf(xrow[c + 1], xrow[c + 1], p1);
            p2 = fmaf(xrow[c + 2], xrow[c + 2], p2);
            p3 = fmaf(xrow[c + 3], xrow[c + 3], p3);
        }
        const float xsq = __fadd_rn(__fadd_rn(p0, p1), __fadd_rn(p2, p3));
        float best = 3.4e38f; int bk = 1 << 30;
        for (int t = 0; t < 8; ++t) {
            const int k = lane + 64 * t;
            const float* wk = w + (size_t)k * DIM;
            float d = 0.f;
#pragma unroll
            for (int c = 0; c < DIM; ++c) d = fmaf(xrow[c], wk[c], d);
            const float s = __fsub_rn(__fadd_rn(xsq, swsq_g[k]),
                                      __fmul_rn(2.f, d));
            if (s < best || (s == best && k < bk)) { best = s; bk = k; }
        }
#pragma unroll
        for (int d = 1; d < 64; d <<= 1) {
            float ob = __shfl_xor(best, d);
            int   oi = __shfl_xor(bk, d);
            if (ob < best || (ob == best && oi < bk)) { best = ob; bk = oi; }
        }
        if (lane == 0) out_idx[n] = (float)bk;
        __syncthreads();
    }
}

// Phase 3: epilogue for flagged rows (quantized write, loss, histogram).
__global__ __launch_bounds__(64) void vq_flagfix(
        const float* __restrict__ x, const float* __restrict__ w,
        const unsigned* __restrict__ nflag, const unsigned* __restrict__ flaglist,
        const float* __restrict__ out_idx, float* __restrict__ out_q,
        float* __restrict__ loss_sum, unsigned* __restrict__ counts) {
    const int lane = threadIdx.x;
    const unsigned nf = *nflag;
    for (unsigned fi = blockIdx.x; fi < nf; fi += gridDim.x) {
        const int n = (int)flaglist[fi];
        const int b = n >> 12, hw = n & 4095;
        const int bk = (int)out_idx[n];
        const size_t off = (size_t)b * 262144 + (size_t)lane * 4096 + hw;
        const float wv = w[(size_t)bk * DIM + lane];
        const float xv = x[off];
        out_q[off] = wv;
        float e = wv - xv;
        float e2 = e * e;
#pragma unroll
        for (int d = 32; d > 0; d >>= 1) e2 += __shfl_down(e2, d);
        if (lane == 0) { atomicAdd(loss_sum, e2); atomicAdd(&counts[bk], 1u); }
    }
}

__global__ __launch_bounds__(512) void vq_final(
        const unsigned* __restrict__ counts,
        const float* __restrict__ loss_sum,
        float* __restrict__ out) {
    __shared__ float red[8];
    const int tid = threadIdx.x;
    float p = (float)counts[tid] * (1.f / (float)NROWS);  // /131072 exact
    float t = p * logf(p + 1e-10f);
#pragma unroll
    for (int off = 32; off > 0; off >>= 1) t += __shfl_down(t, off);
    if ((tid & 63) == 0) red[tid >> 6] = t;
    __syncthreads();
    if (tid == 0) {
        float s = 0.f;
#pragma unroll
        for (int i = 0; i < 8; ++i) s += red[i];
        out[PERP_OFF] = expf(-s);
        // loss = q_latent + 0.25*e_latent = 1.25 * MSE (forward values equal)
        out[0] = loss_sum[0] * (1.25f / (float)NELEM);
    }
}

extern "C" void kernel_launch(void* const* d_in, const int* in_sizes, int n_in,
                              void* d_out, int out_size, void* d_ws, size_t ws_size,
                              hipStream_t stream) {
    const float* x = (const float*)d_in[0];
    const float* w = (const float*)d_in[1];
    float* out = (float*)d_out;
    char* ws = (char*)d_ws;
    float*    loss_sum = (float*)ws;
    unsigned* nflag    = (unsigned*)(ws + 4);
    unsigned* counts   = (unsigned*)(ws + 16);
    float*    swsq_g   = (float*)(ws + 4096);
    unsigned short* wpack = (unsigned short*)(ws + 8192);
    unsigned* flaglist = (unsigned*)(ws + 139264);

    // ws re-poisoned to 0xAA each launch: zero loss/nflag/counts.
    hipMemsetAsync(d_ws, 0, 2064, stream);

    vq_prep<<<32, 256, 0, stream>>>(w, swsq_g, wpack);
    vq_phase1<<<NROWS / 128, 256, 0, stream>>>(x, w, swsq_g, (const uint4*)wpack,
                                               out + Q_OFF, out + IDX_OFF,
                                               loss_sum, counts, nflag, flaglist);
    vq_exact<<<1024, 64, 0, stream>>>(x, w, swsq_g, nflag, flaglist, out + IDX_OFF);
    vq_flagfix<<<1024, 64, 0, stream>>>(x, w, nflag, flaglist, out + IDX_OFF,
                                        out + Q_OFF, loss_sum, counts);
    vq_final<<<1, 512, 0, stream>>>(counts, loss_sum, out);
}